// Round 5
// baseline (320.714 us; speedup 1.0000x reference)
//
#include <hip/hip_runtime.h>
#include <cstdint>
#include <cstddef>

// Problem constants
#define BB    8
#define HH    32
#define WW    32
#define TT    4
#define DD    768
#define N0    1408
#define N1    336
#define N2    84
#define NTOK  1828
#define TOK_FLOATS (BB*NTOK*DD)        // 11231232
#define KDIM  3072                     // 4 pixels * 768 ch
#define M1    (BB*N1)                  // 2688
#define M2A   (BB*N2*4)                // 2688
#define M2B   (BB*N2)                  // 672

typedef __attribute__((ext_vector_type(8))) short          short8v; // 8 bf16 MFMA frag
typedef __attribute__((ext_vector_type(8))) unsigned short us8;     // 16B staging
typedef __attribute__((ext_vector_type(4))) float          f32x4;   // MFMA acc

__device__ __forceinline__ unsigned short f2bf(float f) {   // RNE fp32->bf16
    unsigned int u = __float_as_uint(f);
    u += 0x7fffu + ((u >> 16) & 1u);
    return (unsigned short)(u >> 16);
}

// ---------------------------------------------------------------------------
// positions: harness reads whole d_out as float32 -> write FLOAT values.
// (round-3 evidence: int bit-patterns read as denormals, absmax == max|ref|)
// ---------------------------------------------------------------------------
__global__ __launch_bounds__(256) void positions_kernel(
    const int* __restrict__ d0, const int* __restrict__ d1,
    const int* __restrict__ d2, float* __restrict__ pos)
{
    int n = blockIdx.x * 256 + threadIdx.x;
    if (n >= NTOK) return;
    int y, x, t, s;
    if (n < N0)           { y = d0[n*3];         x = d0[n*3+1];         t = d0[n*3+2];         s = 1; }
    else if (n < N0+N1)   { int m = n - N0;      y = d1[m*3]; x = d1[m*3+1]; t = d1[m*3+2];    s = 2; }
    else                  { int m = n - N0 - N1; y = d2[m*3]; x = d2[m*3+1]; t = d2[m*3+2];    s = 4; }
    pos[n*4+0] = (float)y; pos[n*4+1] = (float)x; pos[n*4+2] = (float)s; pos[n*4+3] = (float)t;
}

// ---------------------------------------------------------------------------
// tok0 gather (fp32 passthrough — validated in round 3)
// ---------------------------------------------------------------------------
__global__ __launch_bounds__(256) void gather0_kernel(
    const float* __restrict__ base, const int* __restrict__ d0,
    float* __restrict__ out)
{
    const int total = BB * N0 * (DD/4);
    for (int idx = blockIdx.x * 256 + threadIdx.x; idx < total; idx += gridDim.x * 256) {
        int d4 = idx % (DD/4);
        int nb = idx / (DD/4);
        int n  = nb % N0;
        int b  = nb / N0;
        int y = d0[n*3], x = d0[n*3+1], t = d0[n*3+2];
        const float4* src = (const float4*)(base + (size_t)(((b*HH + y)*WW + x)*TT + t) * DD) + d4;
        float4*       dst = (float4*)(out + ((size_t)b*NTOK + n) * DD) + d4;
        *dst = *src;
    }
}

// ---------------------------------------------------------------------------
// weight transpose+cast: w[d][c][i][j] -> Wtb[n=d][k=p*768+c] bf16 (n-major)
// gridDim.z selects which of up to 3 weights; one launch for all.
// ---------------------------------------------------------------------------
__global__ __launch_bounds__(256) void castW_kernel(
    const float* __restrict__ wA, unsigned short* __restrict__ oA,
    const float* __restrict__ wB, unsigned short* __restrict__ oB,
    const float* __restrict__ wC, unsigned short* __restrict__ oC)
{
    const float* w; unsigned short* Wtb;
    if      (blockIdx.z == 0) { w = wA; Wtb = oA; }
    else if (blockIdx.z == 1) { w = wB; Wtb = oB; }
    else                      { w = wC; Wtb = oC; }
    int idx = blockIdx.x * 256 + threadIdx.x;   // output index, 768*3072 exact
    int n = idx / KDIM;
    int r = idx - n * KDIM;
    int p = r / DD;
    int c = r - p * DD;
    Wtb[idx] = f2bf(w[n*KDIM + c*4 + p]);
}

// ---------------------------------------------------------------------------
// gather+cast A rows to packed bf16 [m][3072], k=(i*2+j)*768+c
//   rm < M1:  desc1 token (2x2 at (y+i, x+j))          -> A1[m]
//   rm >= M1: desc2 (b,n,h,w) pixel (y+2h+i, x+2w+j)   -> A2[m-M1]
// half: 0=both (8064 blk), 1=first only (4032), 2=second only (4032)
// ---------------------------------------------------------------------------
__global__ __launch_bounds__(256) void gatherA_kernel(
    const float* __restrict__ base, const int* __restrict__ d1,
    const int* __restrict__ d2, unsigned short* __restrict__ A1,
    unsigned short* __restrict__ A2, int half)
{
    int idx = blockIdx.x * 256 + threadIdx.x;
    int rm = idx / 384;                 // 384 octets per 3072-row
    int o  = idx - rm * 384;
    if (half == 2) rm += M1;
    int k0 = o * 8;
    int p  = k0 / DD, c0 = k0 - p * DD;
    const float* rowp;
    unsigned short* dst;
    if (rm < M1) {
        int m = rm, b = m / N1, tok = m - b * N1;
        int y = d1[tok*3] + (p>>1), x = d1[tok*3+1] + (p&1), t = d1[tok*3+2];
        rowp = base + (size_t)(((b*HH + y)*WW + x)*TT + t) * DD;
        dst  = A1 + (size_t)m * KDIM + k0;
    } else {
        int m = rm - M1, b = m / (N2*4), r = m - b * (N2*4);
        int n = r >> 2, hw = r & 3, h = hw >> 1, w = hw & 1;
        int y = d2[n*3] + 2*h + (p>>1), x = d2[n*3+1] + 2*w + (p&1), t = d2[n*3+2];
        rowp = base + (size_t)(((b*HH + y)*WW + x)*TT + t) * DD;
        dst  = A2 + (size_t)m * KDIM + k0;
    }
    float4 v0 = *(const float4*)(rowp + c0);
    float4 v1 = *(const float4*)(rowp + c0 + 4);
    us8 r8;
    r8[0]=f2bf(v0.x); r8[1]=f2bf(v0.y); r8[2]=f2bf(v0.z); r8[3]=f2bf(v0.w);
    r8[4]=f2bf(v1.x); r8[5]=f2bf(v1.y); r8[6]=f2bf(v1.z); r8[7]=f2bf(v1.w);
    *(us8*)dst = r8;
}

// ---------------------------------------------------------------------------
// bf16 MFMA GEMM: C[M][768] = A[M][3072] (bf16) x Wtb[768][3072]^T (bf16) + bias
// BM=64 BN=128 BK=64, 256 thr = 4 waves (2x2 grid, each wave 32x64 = 2x4 frags).
// LDS rows padded to 144B: 9-quad rotation -> uniform 8 lanes/bank-quad on all
// b128 writes AND reads (hand-verified) = minimum-time LDS, no swizzle needed.
// Register-prefetch double buffer (tile k+1 in regs while tile k computes).
// mode 0: out tokens[b,1408+tok] fp32 | 1: y1b bf16 | 2: tokens[b,1744+n] fp32
// ---------------------------------------------------------------------------
struct GCfg {
    const unsigned short* A;
    const unsigned short* Bw;
    const float*          bias;
    float*                outf;
    unsigned short*       outb;
    int                   M;
    int                   mode;
};

__global__ __launch_bounds__(256) void mfma_gemm_kernel(GCfg c0, GCfg c1)
{
    GCfg cfg = (blockIdx.z == 0) ? c0 : c1;
    constexpr int LDT = 72;                  // padded LDS row stride (ushorts) = 144B
    __shared__ unsigned short As[64  * LDT]; //  9216 B
    __shared__ unsigned short Bs[128 * LDT]; // 18432 B

    const int tid  = threadIdx.x;
    const int lane = tid & 63;
    const int wv   = tid >> 6;
    const int wr   = wv >> 1, wc = wv & 1;   // 2x2 wave grid
    const int m0   = blockIdx.x * 64, n0 = blockIdx.y * 128;

    // staging: A row ar (4 thr/row, 2x16B each); B row br (2 thr/row, 4x16B each)
    const int ar = tid >> 2, aci = (tid & 3) * 2;
    const int br = tid >> 1, bci = (tid & 1) * 4;
    int mrow = m0 + ar; if (mrow >= cfg.M) mrow = cfg.M - 1;
    const unsigned short* aptr = cfg.A  + (size_t)mrow    * KDIM + aci * 8;
    const unsigned short* bptr = cfg.Bw + (size_t)(n0+br) * KDIM + bci * 8;

    f32x4 acc[2][4];
    #pragma unroll
    for (int i = 0; i < 2; ++i)
        #pragma unroll
        for (int j = 0; j < 4; ++j)
            #pragma unroll
            for (int r = 0; r < 4; ++r) acc[i][j][r] = 0.f;

    us8 a0, a1, b0, b1, b2, b3;
    a0 = *(const us8*)(aptr);      a1 = *(const us8*)(aptr + 8);
    b0 = *(const us8*)(bptr);      b1 = *(const us8*)(bptr + 8);
    b2 = *(const us8*)(bptr + 16); b3 = *(const us8*)(bptr + 24);

    for (int k0 = 0; k0 < KDIM; k0 += 64) {
        __syncthreads();                          // prior tile's LDS reads done
        *(us8*)&As[ar*LDT +  aci   *8] = a0;
        *(us8*)&As[ar*LDT + (aci+1)*8] = a1;
        *(us8*)&Bs[br*LDT +  bci   *8] = b0;
        *(us8*)&Bs[br*LDT + (bci+1)*8] = b1;
        *(us8*)&Bs[br*LDT + (bci+2)*8] = b2;
        *(us8*)&Bs[br*LDT + (bci+3)*8] = b3;
        __syncthreads();
        if (k0 + 64 < KDIM) {                     // prefetch next tile under compute
            const unsigned short* ap = aptr + k0 + 64;
            const unsigned short* bp = bptr + k0 + 64;
            a0 = *(const us8*)(ap);      a1 = *(const us8*)(ap + 8);
            b0 = *(const us8*)(bp);      b1 = *(const us8*)(bp + 8);
            b2 = *(const us8*)(bp + 16); b3 = *(const us8*)(bp + 24);
        }
        #pragma unroll
        for (int ks = 0; ks < 2; ++ks) {
            short8v av[2], bv[4];
            #pragma unroll
            for (int fm = 0; fm < 2; ++fm) {
                int row = wr*32 + fm*16 + (lane & 15);
                av[fm] = *(const short8v*)&As[row*LDT + (ks*4 + (lane>>4))*8];
            }
            #pragma unroll
            for (int fn = 0; fn < 4; ++fn) {
                int row = wc*64 + fn*16 + (lane & 15);
                bv[fn] = *(const short8v*)&Bs[row*LDT + (ks*4 + (lane>>4))*8];
            }
            #pragma unroll
            for (int fm = 0; fm < 2; ++fm)
                #pragma unroll
                for (int fn = 0; fn < 4; ++fn)
                    acc[fm][fn] = __builtin_amdgcn_mfma_f32_16x16x32_bf16(
                        av[fm], bv[fn], acc[fm][fn], 0, 0, 0);
        }
    }

    // epilogue: D[m][n], m = frag_m + (lane>>4)*4 + reg, n = frag_n + (lane&15)
    const int rg = lane >> 4, col = lane & 15;
    const int mode = cfg.mode;
    #pragma unroll
    for (int fm = 0; fm < 2; ++fm) {
        #pragma unroll
        for (int fn = 0; fn < 4; ++fn) {
            int n = n0 + wc*64 + fn*16 + col;
            float bs = cfg.bias[n];
            #pragma unroll
            for (int r = 0; r < 4; ++r) {
                int m = m0 + wr*32 + fm*16 + rg*4 + r;
                if (m >= cfg.M) continue;
                float v = acc[fm][fn][r] + bs;
                if (mode == 0) {
                    int b = m / N1, tok = m - b*N1;
                    cfg.outf[((size_t)b*NTOK + N0 + tok)*DD + n] = v;
                } else if (mode == 1) {
                    cfg.outb[(size_t)m*DD + n] = f2bf(v);
                } else {
                    int b = m / N2, tk = m - b*N2;
                    cfg.outf[((size_t)b*NTOK + N0 + N1 + tk)*DD + n] = v;
                }
            }
        }
    }
}

// ---------------------------------------------------------------------------
extern "C" void kernel_launch(void* const* d_in, const int* in_sizes, int n_in,
                              void* d_out, int out_size, void* d_ws, size_t ws_size,
                              hipStream_t stream)
{
    const float* base  = (const float*)d_in[0];
    const int*   desc0 = (const int*)  d_in[1];
    const int*   desc1 = (const int*)  d_in[2];
    const int*   desc2 = (const int*)  d_in[3];
    const float* w1    = (const float*)d_in[4];
    const float* b1    = (const float*)d_in[5];
    const float* w2a   = (const float*)d_in[6];
    const float* b2a   = (const float*)d_in[7];
    const float* w2b   = (const float*)d_in[8];
    const float* b2b   = (const float*)d_in[9];

    float* out = (float*)d_out;
    float* pos = (float*)d_out + TOK_FLOATS;
    unsigned short* ws = (unsigned short*)d_ws;

    positions_kernel<<<8, 256, 0, stream>>>(desc0, desc1, desc2, pos);
    gather0_kernel<<<2048, 256, 0, stream>>>(base, desc0, out);

    const size_t ABF = (size_t)M1 * KDIM;    // 8257536 us
    const size_t WTB = (size_t)DD * KDIM;    // 2359296 us
    const size_t Y1  = (size_t)M2A * DD;     // 2064384 us
    const size_t need_full = (2*ABF + Y1 + 3*WTB) * sizeof(unsigned short); // ~51.3 MB

    if (ws_size >= need_full) {
        unsigned short* A1  = ws;
        unsigned short* A2  = A1  + ABF;
        unsigned short* y1b = A2  + ABF;
        unsigned short* W1  = y1b + Y1;
        unsigned short* W2a = W1  + WTB;
        unsigned short* W2b = W2a + WTB;
        castW_kernel<<<dim3(9216, 1, 3), 256, 0, stream>>>(w1, W1, w2a, W2a, w2b, W2b);
        gatherA_kernel<<<8064, 256, 0, stream>>>(base, desc1, desc2, A1, A2, 0);
        GCfg cA = { A1, W1,  b1,  out,     nullptr, M1,  0 };
        GCfg cB = { A2, W2a, b2a, nullptr, y1b,     M2A, 1 };
        mfma_gemm_kernel<<<dim3(42, 6, 2), 256, 0, stream>>>(cA, cB);
        GCfg cC = { y1b, W2b, b2b, out, nullptr, M2B, 2 };
        mfma_gemm_kernel<<<dim3(11, 6, 1), 256, 0, stream>>>(cC, cC);
    } else {
        // sequential fallback, buffers reused (~25.4 MB)
        unsigned short* A1  = ws;
        unsigned short* Wt  = A1 + ABF;
        unsigned short* y1b = Wt + WTB;
        castW_kernel<<<dim3(9216, 1, 1), 256, 0, stream>>>(w1, Wt, w1, Wt, w1, Wt);
        gatherA_kernel<<<4032, 256, 0, stream>>>(base, desc1, desc2, A1, A1, 1);
        GCfg cA = { A1, Wt, b1, out, nullptr, M1, 0 };
        mfma_gemm_kernel<<<dim3(42, 6, 1), 256, 0, stream>>>(cA, cA);
        castW_kernel<<<dim3(9216, 1, 1), 256, 0, stream>>>(w2a, Wt, w2a, Wt, w2a, Wt);
        gatherA_kernel<<<4032, 256, 0, stream>>>(base, desc1, desc2, A1, A1, 2);
        GCfg cB = { A1, Wt, b2a, nullptr, y1b, M2A, 1 };
        mfma_gemm_kernel<<<dim3(42, 6, 1), 256, 0, stream>>>(cB, cB);
        castW_kernel<<<dim3(9216, 1, 1), 256, 0, stream>>>(w2b, Wt, w2b, Wt, w2b, Wt);
        GCfg cC = { y1b, Wt, b2b, out, nullptr, M2B, 2 };
        mfma_gemm_kernel<<<dim3(11, 6, 1), 256, 0, stream>>>(cC, cC);
    }
}

// Round 6
// 305.889 us; speedup vs baseline: 1.0485x; 1.0485x over previous
//
#include <hip/hip_runtime.h>
#include <cstdint>
#include <cstddef>

// Problem constants
#define BB    8
#define HH    32
#define WW    32
#define TT    4
#define DD    768
#define N0    1408
#define N1    336
#define N2    84
#define NTOK  1828
#define TOK_FLOATS (BB*NTOK*DD)        // 11231232
#define KDIM  3072                     // 4 pixels * 768 ch
#define M1    (BB*N1)                  // 2688
#define M2A   (BB*N2*4)                // 2688
#define M2B   (BB*N2)                  // 672

typedef __attribute__((ext_vector_type(8))) short          short8v; // 8 bf16 MFMA frag
typedef __attribute__((ext_vector_type(8))) unsigned short us8;     // 16B staging
typedef __attribute__((ext_vector_type(4))) float          f32x4;   // MFMA acc

__device__ __forceinline__ unsigned short f2bf(float f) {   // RNE fp32->bf16
    unsigned int u = __float_as_uint(f);
    u += 0x7fffu + ((u >> 16) & 1u);
    return (unsigned short)(u >> 16);
}

// ---------------------------------------------------------------------------
// positions: harness reads whole d_out as float32 -> FLOAT values (validated r5)
// ---------------------------------------------------------------------------
__global__ __launch_bounds__(256) void positions_kernel(
    const int* __restrict__ d0, const int* __restrict__ d1,
    const int* __restrict__ d2, float* __restrict__ pos)
{
    int n = blockIdx.x * 256 + threadIdx.x;
    if (n >= NTOK) return;
    int y, x, t, s;
    if (n < N0)           { y = d0[n*3];         x = d0[n*3+1];         t = d0[n*3+2];         s = 1; }
    else if (n < N0+N1)   { int m = n - N0;      y = d1[m*3]; x = d1[m*3+1]; t = d1[m*3+2];    s = 2; }
    else                  { int m = n - N0 - N1; y = d2[m*3]; x = d2[m*3+1]; t = d2[m*3+2];    s = 4; }
    pos[n*4+0] = (float)y; pos[n*4+1] = (float)x; pos[n*4+2] = (float)s; pos[n*4+3] = (float)t;
}

// ---------------------------------------------------------------------------
// tok0 gather (validated r5)
// ---------------------------------------------------------------------------
__global__ __launch_bounds__(256) void gather0_kernel(
    const float* __restrict__ base, const int* __restrict__ d0,
    float* __restrict__ out)
{
    const int total = BB * N0 * (DD/4);
    for (int idx = blockIdx.x * 256 + threadIdx.x; idx < total; idx += gridDim.x * 256) {
        int d4 = idx % (DD/4);
        int nb = idx / (DD/4);
        int n  = nb % N0;
        int b  = nb / N0;
        int y = d0[n*3], x = d0[n*3+1], t = d0[n*3+2];
        const float4* src = (const float4*)(base + (size_t)(((b*HH + y)*WW + x)*TT + t) * DD) + d4;
        float4*       dst = (float4*)(out + ((size_t)b*NTOK + n) * DD) + d4;
        *dst = *src;
    }
}

// ---------------------------------------------------------------------------
// weight transpose+cast, coalesced both sides:
// lane = one (d,c): reads float4 w[d*3072 + c*4 .. +3] (16B/lane contiguous),
// writes Wtb[d*3072 + p*768 + c] for p=0..3 (per-p, lanes consecutive c = 128B).
// Same mapping as validated r5 castW, better access pattern. z selects weight.
// ---------------------------------------------------------------------------
__global__ __launch_bounds__(256) void castW_kernel(
    const float* __restrict__ wA, unsigned short* __restrict__ oA,
    const float* __restrict__ wB, unsigned short* __restrict__ oB,
    const float* __restrict__ wC, unsigned short* __restrict__ oC)
{
    const float* w; unsigned short* Wtb;
    if      (blockIdx.z == 0) { w = wA; Wtb = oA; }
    else if (blockIdx.z == 1) { w = wB; Wtb = oB; }
    else                      { w = wC; Wtb = oC; }
    int idx = blockIdx.x * 256 + threadIdx.x;   // (d,c) pairs: 768*768 exact
    int d = idx / DD;
    int c = idx - d * DD;
    float4 v = *(const float4*)(w + (size_t)d * KDIM + c * 4);
    unsigned short* o = Wtb + (size_t)d * KDIM + c;
    o[0*DD] = f2bf(v.x); o[1*DD] = f2bf(v.y); o[2*DD] = f2bf(v.z); o[3*DD] = f2bf(v.w);
}

// ---------------------------------------------------------------------------
// gather+cast A rows to packed bf16 [m][3072], k=(i*2+j)*768+c  (validated r5)
// ---------------------------------------------------------------------------
__global__ __launch_bounds__(256) void gatherA_kernel(
    const float* __restrict__ base, const int* __restrict__ d1,
    const int* __restrict__ d2, unsigned short* __restrict__ A1,
    unsigned short* __restrict__ A2, int half)
{
    int idx = blockIdx.x * 256 + threadIdx.x;
    int rm = idx / 384;                 // 384 octets per 3072-row
    int o  = idx - rm * 384;
    if (half == 2) rm += M1;
    int k0 = o * 8;
    int p  = k0 / DD, c0 = k0 - p * DD;
    const float* rowp;
    unsigned short* dst;
    if (rm < M1) {
        int m = rm, b = m / N1, tok = m - b * N1;
        int y = d1[tok*3] + (p>>1), x = d1[tok*3+1] + (p&1), t = d1[tok*3+2];
        rowp = base + (size_t)(((b*HH + y)*WW + x)*TT + t) * DD;
        dst  = A1 + (size_t)m * KDIM + k0;
    } else {
        int m = rm - M1, b = m / (N2*4), r = m - b * (N2*4);
        int n = r >> 2, hw = r & 3, h = hw >> 1, w = hw & 1;
        int y = d2[n*3] + 2*h + (p>>1), x = d2[n*3+1] + 2*w + (p&1), t = d2[n*3+2];
        rowp = base + (size_t)(((b*HH + y)*WW + x)*TT + t) * DD;
        dst  = A2 + (size_t)m * KDIM + k0;
    }
    float4 v0 = *(const float4*)(rowp + c0);
    float4 v1 = *(const float4*)(rowp + c0 + 4);
    us8 r8;
    r8[0]=f2bf(v0.x); r8[1]=f2bf(v0.y); r8[2]=f2bf(v0.z); r8[3]=f2bf(v0.w);
    r8[4]=f2bf(v1.x); r8[5]=f2bf(v1.y); r8[6]=f2bf(v1.z); r8[7]=f2bf(v1.w);
    *(us8*)dst = r8;
}

// ---------------------------------------------------------------------------
// bf16 MFMA GEMM v2: C[M][768] = A[M][3072] x Bw[768][3072]^T + bias
// BM=128 BN=128 BK=96, 512 thr = 8 waves (2x4), wave tile 64x32 (4x2 frags).
// LDT=104 ushorts (208B): quad advance 5/row (coprime 8) -> perfectly even
// 8-lanes/bank-quad on every b128 read AND write (hand-verified).
// Register prefetch: compute/iter (~930 CU-cy) >= HBM latency -> barrier
// vmcnt(0) drain no longer stalls (r5: 3083 cy/iter vs ~620 of work).
// XCD-chunked bijective swizzle (m204): same-n-panel blocks share an XCD's L2.
// mode 0: tokens[b,1408+tok] f32 | 1: y1b bf16 | 2: tokens[b,1744+n] f32
// ---------------------------------------------------------------------------
struct GCfg {
    const unsigned short* A;
    const unsigned short* Bw;
    const float*          bias;
    float*                outf;
    unsigned short*       outb;
    int                   M;
    int                   mode;
};

__global__ __launch_bounds__(512) void mfma_gemm_kernel(
    GCfg c0, GCfg c1, int nper, int mblks, int swz)
{
    constexpr int BK = 96, LDT = 104;
    __shared__ unsigned short As[128 * LDT];   // 26624 B
    __shared__ unsigned short Bs[128 * LDT];   // 26624 B

    // --- block id -> (gemm, mb, nb), XCD-chunked, m-major within n-panel ---
    int wgid = blockIdx.x;
    if (swz) {
        int nwg = gridDim.x;
        int q = nwg >> 3, r = nwg & 7;
        int xcd = wgid & 7, k = wgid >> 3;
        wgid = (xcd < r ? xcd * (q + 1) : r * (q + 1) + (xcd - r) * q) + k;
    }
    GCfg cfg = c0;
    if (wgid >= nper) { cfg = c1; wgid -= nper; }
    const int nb = wgid / mblks, mb = wgid - nb * mblks;
    const int m0 = mb * 128, n0 = nb * 128;

    const int tid  = threadIdx.x;
    const int lane = tid & 63;
    const int wv   = tid >> 6;              // 0..7
    const int wr   = wv >> 2, wc = wv & 3;  // 2 x 4 wave grid
    const int lr   = lane & 15, lq = lane >> 4;

    // staging: row ar (4 thr/row), 3 octets (16B) each at o = ac + 4k
    const int ar = tid >> 2, ac = tid & 3;
    int mrow = m0 + ar; if (mrow >= cfg.M) mrow = cfg.M - 1;
    const unsigned short* aptr = cfg.A  + (size_t)mrow     * KDIM;
    const unsigned short* bptr = cfg.Bw + (size_t)(n0 + ar) * KDIM;

    f32x4 acc[4][2];
    #pragma unroll
    for (int i = 0; i < 4; ++i)
        #pragma unroll
        for (int j = 0; j < 2; ++j)
            #pragma unroll
            for (int r = 0; r < 4; ++r) acc[i][j][r] = 0.f;

    us8 areg[3], breg[3];
    #pragma unroll
    for (int k = 0; k < 3; ++k) {
        int off = (ac + 4*k) * 8;
        areg[k] = *(const us8*)(aptr + off);
        breg[k] = *(const us8*)(bptr + off);
    }

    for (int k0 = 0; k0 < KDIM; k0 += BK) {
        __syncthreads();                       // prior tile's LDS reads done
        #pragma unroll
        for (int k = 0; k < 3; ++k) {
            int o = ac + 4*k;
            *(us8*)&As[ar*LDT + o*8] = areg[k];
            *(us8*)&Bs[ar*LDT + o*8] = breg[k];
        }
        __syncthreads();
        if (k0 + BK < KDIM) {                  // prefetch next tile into regs
            #pragma unroll
            for (int k = 0; k < 3; ++k) {
                int off = k0 + BK + (ac + 4*k) * 8;
                areg[k] = *(const us8*)(aptr + off);
                breg[k] = *(const us8*)(bptr + off);
            }
        }
        #pragma unroll
        for (int ks = 0; ks < 3; ++ks) {
            short8v av[4], bv[2];
            #pragma unroll
            for (int fm = 0; fm < 4; ++fm)
                av[fm] = *(const short8v*)&As[(wr*64 + fm*16 + lr)*LDT + (ks*4 + lq)*8];
            #pragma unroll
            for (int fn = 0; fn < 2; ++fn)
                bv[fn] = *(const short8v*)&Bs[(wc*32 + fn*16 + lr)*LDT + (ks*4 + lq)*8];
            #pragma unroll
            for (int fm = 0; fm < 4; ++fm)
                #pragma unroll
                for (int fn = 0; fn < 2; ++fn)
                    acc[fm][fn] = __builtin_amdgcn_mfma_f32_16x16x32_bf16(
                        av[fm], bv[fn], acc[fm][fn], 0, 0, 0);
        }
    }

    // epilogue: m = m0 + wr*64 + fm*16 + lq*4 + r ; n = n0 + wc*32 + fn*16 + lr
    const int mode = cfg.mode;
    #pragma unroll
    for (int fm = 0; fm < 4; ++fm) {
        #pragma unroll
        for (int fn = 0; fn < 2; ++fn) {
            int n = n0 + wc*32 + fn*16 + lr;
            float bs = cfg.bias[n];
            #pragma unroll
            for (int r = 0; r < 4; ++r) {
                int m = m0 + wr*64 + fm*16 + lq*4 + r;
                if (m >= cfg.M) continue;
                float v = acc[fm][fn][r] + bs;
                if (mode == 0) {
                    int b = m / N1, tok = m - b*N1;
                    cfg.outf[((size_t)b*NTOK + N0 + tok)*DD + n] = v;
                } else if (mode == 1) {
                    cfg.outb[(size_t)m*DD + n] = f2bf(v);
                } else {
                    int b = m / N2, tk = m - b*N2;
                    cfg.outf[((size_t)b*NTOK + N0 + N1 + tk)*DD + n] = v;
                }
            }
        }
    }
}

// ---------------------------------------------------------------------------
extern "C" void kernel_launch(void* const* d_in, const int* in_sizes, int n_in,
                              void* d_out, int out_size, void* d_ws, size_t ws_size,
                              hipStream_t stream)
{
    const float* base  = (const float*)d_in[0];
    const int*   desc0 = (const int*)  d_in[1];
    const int*   desc1 = (const int*)  d_in[2];
    const int*   desc2 = (const int*)  d_in[3];
    const float* w1    = (const float*)d_in[4];
    const float* b1    = (const float*)d_in[5];
    const float* w2a   = (const float*)d_in[6];
    const float* b2a   = (const float*)d_in[7];
    const float* w2b   = (const float*)d_in[8];
    const float* b2b   = (const float*)d_in[9];

    float* out = (float*)d_out;
    float* pos = (float*)d_out + TOK_FLOATS;
    unsigned short* ws = (unsigned short*)d_ws;

    positions_kernel<<<8, 256, 0, stream>>>(desc0, desc1, desc2, pos);
    gather0_kernel<<<2048, 256, 0, stream>>>(base, desc0, out);

    const size_t ABF = (size_t)M1 * KDIM;    // 8257536 us
    const size_t WTB = (size_t)DD * KDIM;    // 2359296 us
    const size_t Y1  = (size_t)M2A * DD;     // 2064384 us
    const size_t need_full = (2*ABF + Y1 + 3*WTB) * sizeof(unsigned short); // ~51.3 MB

    if (ws_size >= need_full) {
        unsigned short* A1  = ws;
        unsigned short* A2  = A1  + ABF;
        unsigned short* y1b = A2  + ABF;
        unsigned short* W1  = y1b + Y1;
        unsigned short* W2a = W1  + WTB;
        unsigned short* W2b = W2a + WTB;
        castW_kernel<<<dim3(2304, 1, 3), 256, 0, stream>>>(w1, W1, w2a, W2a, w2b, W2b);
        gatherA_kernel<<<8064, 256, 0, stream>>>(base, desc1, desc2, A1, A2, 0);
        // fused: GEMM1 (21x6 blocks) + GEMM2a (21x6) in one 252-block launch
        GCfg cA = { A1, W1,  b1,  out,     nullptr, M1,  0 };
        GCfg cB = { A2, W2a, b2a, nullptr, y1b,     M2A, 1 };
        mfma_gemm_kernel<<<252, 512, 0, stream>>>(cA, cB, 126, 21, 1);
        // stage b: M=672 -> 6x6 = 36 blocks
        GCfg cC = { y1b, W2b, b2b, out, nullptr, M2B, 2 };
        mfma_gemm_kernel<<<36, 512, 0, stream>>>(cC, cC, 36, 6, 0);
    } else {
        // sequential fallback, buffers reused (~25.4 MB)
        unsigned short* A1  = ws;
        unsigned short* Wt  = A1 + ABF;
        unsigned short* y1b = Wt + WTB;
        castW_kernel<<<dim3(2304, 1, 1), 256, 0, stream>>>(w1, Wt, w1, Wt, w1, Wt);
        gatherA_kernel<<<4032, 256, 0, stream>>>(base, desc1, desc2, A1, A1, 1);
        GCfg cA = { A1, Wt, b1, out, nullptr, M1, 0 };
        mfma_gemm_kernel<<<126, 512, 0, stream>>>(cA, cA, 126, 21, 1);
        castW_kernel<<<dim3(2304, 1, 1), 256, 0, stream>>>(w2a, Wt, w2a, Wt, w2a, Wt);
        gatherA_kernel<<<4032, 256, 0, stream>>>(base, desc1, desc2, A1, A1, 2);
        GCfg cB = { A1, Wt, b2a, nullptr, y1b, M2A, 1 };
        mfma_gemm_kernel<<<126, 512, 0, stream>>>(cB, cB, 126, 21, 1);
        castW_kernel<<<dim3(2304, 1, 1), 256, 0, stream>>>(w2b, Wt, w2b, Wt, w2b, Wt);
        GCfg cC = { y1b, Wt, b2b, out, nullptr, M2B, 2 };
        mfma_gemm_kernel<<<36, 512, 0, stream>>>(cC, cC, 36, 6, 0);
    }
}

// Round 7
// 296.435 us; speedup vs baseline: 1.0819x; 1.0319x over previous
//
#include <hip/hip_runtime.h>
#include <cstdint>
#include <cstddef>

// Problem constants
#define BB    8
#define HH    32
#define WW    32
#define TT    4
#define DD    768
#define N0    1408
#define N1    336
#define N2    84
#define NTOK  1828
#define TOK_FLOATS (BB*NTOK*DD)        // 11231232
#define KDIM  3072                     // 4 pixels * 768 ch
#define M1    (BB*N1)                  // 2688
#define M2A   (BB*N2*4)                // 2688
#define M2B   (BB*N2)                  // 672

typedef __attribute__((ext_vector_type(8))) short          short8v; // 8 bf16 MFMA frag
typedef __attribute__((ext_vector_type(8))) unsigned short us8;     // 16B staging
typedef __attribute__((ext_vector_type(4))) float          f32x4;   // MFMA acc

__device__ __forceinline__ unsigned short f2bf(float f) {   // RNE fp32->bf16
    unsigned int u = __float_as_uint(f);
    u += 0x7fffu + ((u >> 16) & 1u);
    return (unsigned short)(u >> 16);
}

// async 16B global->LDS DMA (writes LDS at wave-uniform base + lane*16)
__device__ __forceinline__ void cp16(const unsigned short* g, unsigned short* l) {
    __builtin_amdgcn_global_load_lds(
        (const __attribute__((address_space(1))) unsigned int*)(const void*)g,
        (__attribute__((address_space(3))) unsigned int*)(void*)l,
        16, 0, 0);
}

// ---------------------------------------------------------------------------
// prep mega-kernel: gatherA (8064 blk) | castW x3 (6912) | gather0 (2048) |
// positions (8).  One launch replaces four.
// Swizzle baked into A1/A2/W*: within each 8-octet (128B) k-segment of row r,
// stored octet o holds source octet o ^ (r&7)  (involution; GEMM reads XOR back)
// ---------------------------------------------------------------------------
#define GA_BLKS 8064
#define CW_BLKS 6912   // 3 x 2304
#define G0_BLKS 2048
#define PREP_BLKS (GA_BLKS + CW_BLKS + G0_BLKS + 8)   // 17032

__global__ __launch_bounds__(256) void prep_kernel(
    const float* __restrict__ base, const int* __restrict__ d0,
    const int* __restrict__ d1, const int* __restrict__ d2,
    const float* __restrict__ w1, const float* __restrict__ w2a,
    const float* __restrict__ w2b,
    unsigned short* __restrict__ A1, unsigned short* __restrict__ A2,
    unsigned short* __restrict__ W1, unsigned short* __restrict__ W2a,
    unsigned short* __restrict__ W2b,
    float* __restrict__ out, float* __restrict__ pos)
{
    const int blk = blockIdx.x, tid = threadIdx.x;
    if (blk < GA_BLKS) {
        // ---- gatherA: A rows packed bf16 [m][3072], k=(i*2+j)*768+c, pre-swizzled
        int idx = blk * 256 + tid;
        int rm = idx / 384, o = idx - rm * 384;      // dst octet o of row rm
        int s = (o & ~7) | ((o ^ rm) & 7);           // source octet (key rm&7; 2688%8==0)
        int p = s / 96, c0 = (s - p * 96) * 8;
        const float* rowp;
        unsigned short* dst;
        if (rm < M1) {
            int m = rm, b = m / N1, tok = m - b * N1;
            int y = d1[tok*3] + (p>>1), x = d1[tok*3+1] + (p&1), t = d1[tok*3+2];
            rowp = base + (size_t)(((b*HH + y)*WW + x)*TT + t) * DD;
            dst  = A1 + (size_t)m * KDIM + o * 8;
        } else {
            int m = rm - M1, b = m / (N2*4), r = m - b * (N2*4);
            int n = r >> 2, hw = r & 3, h = hw >> 1, w = hw & 1;
            int y = d2[n*3] + 2*h + (p>>1), x = d2[n*3+1] + 2*w + (p&1), t = d2[n*3+2];
            rowp = base + (size_t)(((b*HH + y)*WW + x)*TT + t) * DD;
            dst  = A2 + (size_t)m * KDIM + o * 8;
        }
        float4 v0 = *(const float4*)(rowp + c0);
        float4 v1 = *(const float4*)(rowp + c0 + 4);
        us8 r8;
        r8[0]=f2bf(v0.x); r8[1]=f2bf(v0.y); r8[2]=f2bf(v0.z); r8[3]=f2bf(v0.w);
        r8[4]=f2bf(v1.x); r8[5]=f2bf(v1.y); r8[6]=f2bf(v1.z); r8[7]=f2bf(v1.w);
        *(us8*)dst = r8;
    } else if (blk < GA_BLKS + CW_BLKS) {
        // ---- castW: w[d][c][i][j] -> Wt[n=d][k=p*768+c'], c' = octet-swizzled by d&7
        int r = blk - GA_BLKS;
        int wsel = r / 2304;
        int idx  = (r - wsel * 2304) * 256 + tid;    // (d,c): 768*768
        const float* w        = wsel==0 ? w1 : (wsel==1 ? w2a : w2b);
        unsigned short* Wt    = wsel==0 ? W1 : (wsel==1 ? W2a : W2b);
        int d = idx / DD, c = idx - d * DD;
        float4 v = *(const float4*)(w + (size_t)d * KDIM + c * 4);
        int csw = (c & ~63) | ((((c>>3) ^ d) & 7) << 3) | (c & 7);
        unsigned short* o = Wt + (size_t)d * KDIM + csw;
        o[0*DD] = f2bf(v.x); o[1*DD] = f2bf(v.y); o[2*DD] = f2bf(v.z); o[3*DD] = f2bf(v.w);
    } else if (blk < GA_BLKS + CW_BLKS + G0_BLKS) {
        // ---- gather0 (fp32 passthrough, validated)
        int bl = blk - GA_BLKS - CW_BLKS;
        const int total = BB * N0 * (DD/4);
        for (int idx = bl * 256 + tid; idx < total; idx += G0_BLKS * 256) {
            int d4 = idx % (DD/4);
            int nb = idx / (DD/4);
            int n  = nb % N0;
            int b  = nb / N0;
            int y = d0[n*3], x = d0[n*3+1], t = d0[n*3+2];
            const float4* src = (const float4*)(base + (size_t)(((b*HH + y)*WW + x)*TT + t) * DD) + d4;
            float4*       dst = (float4*)(out + ((size_t)b*NTOK + n) * DD) + d4;
            *dst = *src;
        }
    } else {
        // ---- positions (float values; validated r5)
        int n = (blk - GA_BLKS - CW_BLKS - G0_BLKS) * 256 + tid;
        if (n >= NTOK) return;
        int y, x, t, s;
        if (n < N0)         { y = d0[n*3];         x = d0[n*3+1];         t = d0[n*3+2];       s = 1; }
        else if (n < N0+N1) { int m = n - N0;      y = d1[m*3]; x = d1[m*3+1]; t = d1[m*3+2];  s = 2; }
        else                { int m = n - N0 - N1; y = d2[m*3]; x = d2[m*3+1]; t = d2[m*3+2];  s = 4; }
        pos[n*4+0] = (float)y; pos[n*4+1] = (float)x; pos[n*4+2] = (float)s; pos[n*4+3] = (float)t;
    }
}

// ---------------------------------------------------------------------------
// bf16 MFMA GEMM v3 (m97-style staging): C[M][768] = A[M][3072] x Bw^T + bias
// BM=64 BN=128 BK=64, 256 thr = 4 waves 2x2, wave tile 32x64 (r5-validated math).
// global_load_lds 16B DMA into double-buffered LINEAR LDS; counted vmcnt(6);
// raw s_barrier pair per iter (loads stay in flight across barriers).
// Workspace pre-swizzled (octet ^= row&7 per 128B segment); reads XOR back ->
// even 8-lanes/bank on every b128 (hand-verified).
// mode 0: tokens[b,1408+tok] f32 | 1: y1b bf16 (stage-b key (m>>2)&7) |
// mode 2: tokens[b,1744+n] f32
// ---------------------------------------------------------------------------
struct GCfg {
    const unsigned short* A;
    const unsigned short* Bw;
    const float*          bias;
    float*                outf;
    unsigned short*       outb;
    int                   M;
    int                   mode;
};

__global__ __launch_bounds__(256) void mfma_gemm_v3(
    GCfg c0, GCfg c1, int nper, int mblks, int swz)
{
    __shared__ unsigned short As[2][64 * 64];    // 2 x  8 KB
    __shared__ unsigned short Bs[2][128 * 64];   // 2 x 16 KB

    int wgid = blockIdx.x;
    if (swz) wgid = (wgid & 7) * (gridDim.x >> 3) + (wgid >> 3);  // grid % 8 == 0
    GCfg cfg = c0;
    if (wgid >= nper) { cfg = c1; wgid -= nper; }
    const int nb = wgid / mblks, mb = wgid - nb * mblks;
    const int m0 = mb * 64, n0 = nb * 128;

    const int tid = threadIdx.x, lane = tid & 63;
    const int wv = tid >> 6, wr = wv >> 1, wc = wv & 1;   // 2x2 wave grid
    const int lr = lane & 15, lq = lane >> 4, xr = lr & 7;

    // DMA source pointers: thread t, chunk j covers LDS octet j*256+t
    const int aoct = tid & 7, trow = tid >> 3;            // 0..31
    int am0 = m0 + trow;      if (am0 >= cfg.M) am0 = cfg.M - 1;
    int am1 = m0 + 32 + trow; if (am1 >= cfg.M) am1 = cfg.M - 1;
    const unsigned short* ag0 = cfg.A + (size_t)am0 * KDIM + aoct * 8;
    const unsigned short* ag1 = cfg.A + (size_t)am1 * KDIM + aoct * 8;
    const unsigned short* bg0 = cfg.Bw + (size_t)(n0 +      trow) * KDIM + aoct * 8;
    const unsigned short* bg1 = cfg.Bw + (size_t)(n0 + 32 + trow) * KDIM + aoct * 8;
    const unsigned short* bg2 = cfg.Bw + (size_t)(n0 + 64 + trow) * KDIM + aoct * 8;
    const unsigned short* bg3 = cfg.Bw + (size_t)(n0 + 96 + trow) * KDIM + aoct * 8;

    const int wu = tid & 192;   // wave-uniform lane-base (wave*64)

    f32x4 acc[2][4];
    #pragma unroll
    for (int i = 0; i < 2; ++i)
        #pragma unroll
        for (int j = 0; j < 4; ++j)
            #pragma unroll
            for (int r = 0; r < 4; ++r) acc[i][j][r] = 0.f;

    auto STAGE = [&](int buf, int k0) {
        cp16(ag0 + k0, &As[buf][(0*256 + wu) * 8]);
        cp16(ag1 + k0, &As[buf][(1*256 + wu) * 8]);
        cp16(bg0 + k0, &Bs[buf][(0*256 + wu) * 8]);
        cp16(bg1 + k0, &Bs[buf][(1*256 + wu) * 8]);
        cp16(bg2 + k0, &Bs[buf][(2*256 + wu) * 8]);
        cp16(bg3 + k0, &Bs[buf][(3*256 + wu) * 8]);
    };

    STAGE(0, 0);
    constexpr int NIT = KDIM / 64;   // 48
    for (int it = 0; it < NIT; ++it) {
        const int cur = it & 1;
        if (it + 1 < NIT) {
            STAGE(cur ^ 1, (it + 1) * 64);                 // 6 more in flight
            asm volatile("s_waitcnt vmcnt(6)" ::: "memory"); // cur's 6 landed
        } else {
            asm volatile("s_waitcnt vmcnt(0)" ::: "memory");
        }
        __builtin_amdgcn_s_barrier();                      // all waves' cur ready
        const unsigned short* Asb = As[cur];
        const unsigned short* Bsb = Bs[cur];
        #pragma unroll
        for (int ks = 0; ks < 2; ++ks) {
            short8v av[2], bv[4];
            #pragma unroll
            for (int fm = 0; fm < 2; ++fm) {
                int row = wr*32 + fm*16 + lr;
                av[fm] = *(const short8v*)&Asb[row*64 + ((ks*4 + lq) ^ xr) * 8];
            }
            #pragma unroll
            for (int fn = 0; fn < 4; ++fn) {
                int row = wc*64 + fn*16 + lr;
                bv[fn] = *(const short8v*)&Bsb[row*64 + ((ks*4 + lq) ^ xr) * 8];
            }
            #pragma unroll
            for (int fm = 0; fm < 2; ++fm)
                #pragma unroll
                for (int fn = 0; fn < 4; ++fn)
                    acc[fm][fn] = __builtin_amdgcn_mfma_f32_16x16x32_bf16(
                        av[fm], bv[fn], acc[fm][fn], 0, 0, 0);
        }
        __builtin_amdgcn_s_barrier();                      // reads done before overwrite
    }

    // epilogue (r5-validated): m = m0+wr*32+fm*16+lq*4+r ; n = n0+wc*64+fn*16+lr
    const int mode = cfg.mode;
    #pragma unroll
    for (int fm = 0; fm < 2; ++fm) {
        #pragma unroll
        for (int fn = 0; fn < 4; ++fn) {
            int n = n0 + wc*64 + fn*16 + lr;
            float bs = cfg.bias[n];
            #pragma unroll
            for (int r = 0; r < 4; ++r) {
                int m = m0 + wr*32 + fm*16 + lq*4 + r;
                if (m >= cfg.M) continue;
                float v = acc[fm][fn][r] + bs;
                if (mode == 0) {
                    int b = m / N1, tok = m - b*N1;
                    cfg.outf[((size_t)b*NTOK + N0 + tok)*DD + n] = v;
                } else if (mode == 1) {
                    // y1b consumed as stage-b A rows (4 y1 rows = one 3072-row,
                    // stage-b row index m>>2): octet-swizzle with key (m>>2)&7
                    int nsw = (n & ~63) | ((((n>>3) ^ (m>>2)) & 7) << 3) | (n & 7);
                    cfg.outb[(size_t)m*DD + nsw] = f2bf(v);
                } else {
                    int b = m / N2, tk = m - b*N2;
                    cfg.outf[((size_t)b*NTOK + N0 + N1 + tk)*DD + n] = v;
                }
            }
        }
    }
}

// ---------------------------------------------------------------------------
extern "C" void kernel_launch(void* const* d_in, const int* in_sizes, int n_in,
                              void* d_out, int out_size, void* d_ws, size_t ws_size,
                              hipStream_t stream)
{
    const float* base  = (const float*)d_in[0];
    const int*   desc0 = (const int*)  d_in[1];
    const int*   desc1 = (const int*)  d_in[2];
    const int*   desc2 = (const int*)  d_in[3];
    const float* w1    = (const float*)d_in[4];
    const float* b1    = (const float*)d_in[5];
    const float* w2a   = (const float*)d_in[6];
    const float* b2a   = (const float*)d_in[7];
    const float* w2b   = (const float*)d_in[8];
    const float* b2b   = (const float*)d_in[9];

    float* out = (float*)d_out;
    float* pos = (float*)d_out + TOK_FLOATS;
    unsigned short* ws = (unsigned short*)d_ws;

    // workspace layout (ushorts) — same 51.3 MB footprint that ran in r5/r6
    const size_t ABF = (size_t)M1 * KDIM;    // 8257536
    const size_t Y1  = (size_t)M2A * DD;     // 2064384
    const size_t WTB = (size_t)DD * KDIM;    // 2359296
    unsigned short* A1  = ws;
    unsigned short* A2  = A1  + ABF;
    unsigned short* y1b = A2  + ABF;
    unsigned short* W1  = y1b + Y1;
    unsigned short* W2a = W1  + WTB;
    unsigned short* W2b = W2a + WTB;

    prep_kernel<<<PREP_BLKS, 256, 0, stream>>>(
        base, desc0, desc1, desc2, w1, w2a, w2b,
        A1, A2, W1, W2a, W2b, out, pos);

    // fused GEMM1 (M=2688) + GEMM2a (M=2688): 2 x 42 x 6 = 504 blocks (2/CU)
    GCfg cA = { A1, W1,  b1,  out,     nullptr, M1,  0 };
    GCfg cB = { A2, W2a, b2a, nullptr, y1b,     M2A, 1 };
    mfma_gemm_v3<<<504, 256, 0, stream>>>(cA, cB, 252, 42, 1);

    // stage b: M=672 -> 11 x 6 = 66 blocks
    GCfg cC = { y1b, W2b, b2b, out, nullptr, M2B, 2 };
    mfma_gemm_v3<<<66, 256, 0, stream>>>(cC, cC, 66, 11, 0);
}